// Round 1
// baseline (267.474 us; speedup 1.0000x reference)
//
#include <hip/hip_runtime.h>
#include <hip/hip_bf16.h>
#include <cstdint>

// Problem constants (from reference)
#define T_  4
#define B_  32
#define C_  384
#define HF_ 1536
#define HW_ 196
#define E_  8
#define N_  128           // T*B
#define REC_CAP 16384

// ---------------------------------------------------------------------------
// K1: fold BN constants; zero header (rec_count, f_acc, p_acc)
//   A[e][o]  = inv1,  Bc[e][o] = inv1*b1 + (be1 - m1*inv1) - tau
//   spike2 iff A*S + Bc >= 0   (S = sum of w1 over spiking channels)
//   const2[e][c] = b2*inv2 + (be2 - m2*inv2),  inv2v[e][c] = inv2
// ---------------------------------------------------------------------------
__global__ void k_prep(const float* b1, const float* g1, const float* be1,
                       const float* m1, const float* v1,
                       const float* b2, const float* g2, const float* be2,
                       const float* m2, const float* v2,
                       const float* taus,
                       float* A, float* Bc, float* const2, float* inv2v,
                       int* header) {
  int idx = blockIdx.x * 256 + threadIdx.x;
  if (idx < 64) header[idx] = 0;
  if (idx < E_ * HF_) {
    int e = idx / HF_;
    float inv = g1[idx] / sqrtf(v1[idx] + 1e-5f);
    float sh  = be1[idx] - m1[idx] * inv;
    A[idx]  = inv;
    Bc[idx] = inv * b1[idx] + sh - taus[e];
  }
  if (idx < E_ * C_) {
    float inv = g2[idx] / sqrtf(v2[idx] + 1e-5f);
    const2[idx] = b2[idx] * inv + (be2[idx] - m2[idx] * inv);
    inv2v[idx]  = inv;
  }
}

// ---------------------------------------------------------------------------
// K2: LDS-tiled transpose w1 (E,HF,C) -> w1t (E,C,HF) in bf16
// ---------------------------------------------------------------------------
__global__ void k_transpose(const float* __restrict__ w1,
                            __hip_bfloat16* __restrict__ w1t) {
  __shared__ float tile[64][33];
  int e = blockIdx.x, ct = blockIdx.y, ot = blockIdx.z;
  int c0 = ct * 32, o0 = ot * 64;
  int tid = threadIdx.x;
  int cl = tid & 31, olb = tid >> 5;
  #pragma unroll
  for (int it = 0; it < 8; ++it) {
    int ol = olb + it * 8;
    tile[ol][cl] = w1[(size_t)(e * HF_ + o0 + ol) * C_ + c0 + cl];
  }
  __syncthreads();
  int ol2 = tid & 63, clb = tid >> 6;
  #pragma unroll
  for (int it = 0; it < 8; ++it) {
    int cl2 = clb + it * 4;
    w1t[(size_t)(e * C_ + c0 + cl2) * HF_ + o0 + ol2] =
        __float2bfloat16(tile[ol2][cl2]);
  }
}

// ---------------------------------------------------------------------------
// K3: LIF over T, spike counts per (t,b,c) over the 196 positions
// ---------------------------------------------------------------------------
__global__ void k_lif(const float* __restrict__ x, float* __restrict__ cnt) {
  __shared__ int c4[T_];
  int tid = threadIdx.x;
  if (tid < T_) c4[tid] = 0;
  __syncthreads();
  int bc = blockIdx.x;  // b*C + c
  if (tid < HW_) {
    float v = 0.f;
    size_t base = (size_t)bc * HW_ + tid;
    #pragma unroll
    for (int t = 0; t < T_; ++t) {
      float xv = x[base + (size_t)t * B_ * C_ * HW_];
      v = v + (xv - v) * 0.5f;          // tau=2.0 exactly
      if (v - 1.0f >= 0.0f) { atomicAdd(&c4[t], 1); v = 0.f; }
    }
  }
  __syncthreads();
  if (tid < T_) cnt[(size_t)tid * B_ * C_ + bc] = (float)c4[tid];
}

// ---------------------------------------------------------------------------
// K4: router logits -> softmax -> top-2 -> gate; aux accumulators; K[n,c]
// ---------------------------------------------------------------------------
__global__ void k_router(const float* __restrict__ cnt, const float* __restrict__ rw,
                         const float* rb, const float* rg, const float* rbeta,
                         const float* rmean, const float* rvar,
                         const float* __restrict__ const2,
                         int* sel_e, float* sel_g, float* gsum, float* K,
                         float* f_acc, float* p_acc) {
  __shared__ float sc[C_];
  __shared__ float lg[E_];
  __shared__ int s_i1, s_i2;
  __shared__ float s_g1, s_g2;
  int n = blockIdx.x, tid = threadIdx.x;
  for (int c = tid; c < C_; c += 64) sc[c] = cnt[(size_t)n * C_ + c];
  __syncthreads();
  if (tid < E_) {
    float dot = 0.f;
    for (int c = 0; c < C_; ++c) dot += rw[tid * C_ + c] * sc[c];
    float inv = rg[tid] / sqrtf(rvar[tid] + 1e-5f);
    lg[tid] = (dot * (1.0f / HW_) + rb[tid]) * inv + (rbeta[tid] - rmean[tid] * inv);
  }
  __syncthreads();
  if (tid == 0) {
    float m = lg[0];
    for (int e = 1; e < E_; ++e) m = fmaxf(m, lg[e]);
    float p[E_]; float s = 0.f;
    for (int e = 0; e < E_; ++e) { p[e] = expf(lg[e] - m); s += p[e]; }
    float invs = 1.0f / s;
    for (int e = 0; e < E_; ++e) p[e] *= invs;
    int i1 = 0;
    for (int e = 1; e < E_; ++e) if (p[e] > p[i1]) i1 = e;   // first-occurrence max
    int i2 = (i1 == 0) ? 1 : 0;
    for (int e = 0; e < E_; ++e) if (e != i1 && p[e] > p[i2]) i2 = e;
    float w = p[i1] + p[i2];
    float ga = p[i1] / w, gb = p[i2] / w;
    sel_e[2 * n] = i1; sel_e[2 * n + 1] = i2;
    sel_g[2 * n] = ga; sel_g[2 * n + 1] = gb;
    gsum[n] = ga + gb;
    s_i1 = i1; s_i2 = i2; s_g1 = ga; s_g2 = gb;
    atomicAdd(&f_acc[i1], 1.0f);
    atomicAdd(&f_acc[i2], 1.0f);
    for (int e = 0; e < E_; ++e) atomicAdd(&p_acc[e], p[e]);
  }
  __syncthreads();
  int i1 = s_i1, i2 = s_i2; float ga = s_g1, gb = s_g2;
  for (int c = tid; c < C_; c += 64)
    K[(size_t)n * C_ + c] = ga * const2[i1 * C_ + c] + gb * const2[i2 * C_ + c];
}

// ---------------------------------------------------------------------------
// K5 (hot): per (pair, row h): build spike list per position, accumulate
// layer-1 sums from bf16 w1t rows (6 outputs/thread), threshold, record
// the (astronomically rare) layer-2 spikes.
// ---------------------------------------------------------------------------
__global__ __launch_bounds__(256) void k_expert1(
    const float* __restrict__ x, const __hip_bfloat16* __restrict__ w1t,
    const float* __restrict__ A, const float* __restrict__ Bc,
    const int* __restrict__ sel_e, const float* __restrict__ taus,
    int* __restrict__ rec, int* __restrict__ rec_count) {
  __shared__ float xs[C_ * 14];
  __shared__ int slist[C_];
  __shared__ int snnz;
  int pair = blockIdx.x, h = blockIdx.y;
  int n = pair >> 1;
  int e = sel_e[pair];
  int tid = threadIdx.x;
  float tau = taus[e];
  // per-thread BN/threshold constants for my 6 contiguous outputs
  float rA[6], rB[6];
  #pragma unroll
  for (int k = 0; k < 6; ++k) {
    int o = tid * 6 + k;
    rA[k] = A[e * HF_ + o];
    rB[k] = Bc[e * HF_ + o];
  }
  // stage this row of x: xs[c][w]
  for (int idx = tid; idx < C_ * 14; idx += 256) {
    int c = idx / 14, w = idx % 14;
    xs[idx] = x[((size_t)(n * C_ + c) * 14 + h) * 14 + w];
  }
  const uint32_t* wbase = (const uint32_t*)(w1t + (size_t)e * C_ * HF_);
  for (int w = 0; w < 14; ++w) {
    if (tid == 0) snnz = 0;
    __syncthreads();
    for (int c = tid; c < C_; c += 256) {
      if (xs[c * 14 + w] / tau - 1.0f >= 0.0f) {   // s1 = spike(x/tau - 1)
        int pos = atomicAdd(&snnz, 1);
        slist[pos] = c;
      }
    }
    __syncthreads();
    int nnz = snnz;
    float S0 = 0, S1 = 0, S2 = 0, S3 = 0, S4 = 0, S5 = 0;
    for (int j = 0; j < nnz; ++j) {
      int c = slist[j];                              // wave-uniform broadcast
      const uint32_t* row = wbase + c * (HF_ / 2) + tid * 3;
      uint32_t u0 = row[0], u1 = row[1], u2 = row[2];
      S0 += __uint_as_float(u0 << 16);
      S1 += __uint_as_float(u0 & 0xffff0000u);
      S2 += __uint_as_float(u1 << 16);
      S3 += __uint_as_float(u1 & 0xffff0000u);
      S4 += __uint_as_float(u2 << 16);
      S5 += __uint_as_float(u2 & 0xffff0000u);
    }
    float Sv[6] = {S0, S1, S2, S3, S4, S5};
    #pragma unroll
    for (int k = 0; k < 6; ++k) {
      float a = rA[k] * Sv[k] + rB[k];
      if (a >= 0.0f) {                               // layer-2 spike (rare)
        int ridx = atomicAdd(rec_count, 1);
        if (ridx < REC_CAP) {
          rec[ridx * 3 + 0] = pair;
          rec[ridx * 3 + 1] = h * 14 + w;
          rec[ridx * 3 + 2] = tid * 6 + k;
        }
      }
    }
    __syncthreads();
  }
}

// ---------------------------------------------------------------------------
// K6: out = gsum[n]*x + K[n,c]  (float4, memory-bound); writes aux
// ---------------------------------------------------------------------------
__global__ void k_combine(const float* __restrict__ x, const float* __restrict__ gsum,
                          const float* __restrict__ K,
                          const float* f_acc, const float* p_acc,
                          float* __restrict__ out, float* aux_out) {
  const int TOT4 = T_ * B_ * C_ * HW_ / 4;  // 2,408,448
  int i4 = blockIdx.x * 256 + threadIdx.x;
  if (i4 < TOT4) {
    int n = i4 / (C_ * 49);
    int r = i4 - n * (C_ * 49);
    int c = r / 49;
    float4 xv = ((const float4*)x)[i4];
    float g = gsum[n];
    float k = K[n * C_ + c];
    float4 o;
    o.x = g * xv.x + k; o.y = g * xv.y + k;
    o.z = g * xv.z + k; o.w = g * xv.w + k;
    ((float4*)out)[i4] = o;
  }
  if (blockIdx.x == 0 && threadIdx.x == 0) {
    float s = 0.f;
    for (int e = 0; e < E_; ++e)
      s += (f_acc[e] * (1.0f / N_)) * (p_acc[e] * (1.0f / N_));
    *aux_out = 0.01f * E_ * s;
  }
}

// ---------------------------------------------------------------------------
// K7: apply the rare layer-2 spike records: out[n,:,p] += g*inv2*w2[e][:,o]
// ---------------------------------------------------------------------------
__global__ void k_apply(const int* __restrict__ rec, const int* __restrict__ rec_count,
                        const int* __restrict__ sel_e, const float* __restrict__ sel_g,
                        const float* __restrict__ inv2v, const float* __restrict__ w2,
                        float* __restrict__ out) {
  int nrec = *rec_count;
  if (nrec > REC_CAP) nrec = REC_CAP;
  for (int r = blockIdx.x; r < nrec; r += gridDim.x) {
    int pair = rec[r * 3], p = rec[r * 3 + 1], o = rec[r * 3 + 2];
    int n = pair >> 1;
    int e = sel_e[pair];
    float g = sel_g[pair];
    for (int c = threadIdx.x; c < C_; c += blockDim.x) {
      float wv = w2[(size_t)(e * C_ + c) * HF_ + o];
      atomicAdd(&out[(size_t)(n * C_ + c) * HW_ + p], g * inv2v[e * C_ + c] * wv);
    }
  }
}

// ---------------------------------------------------------------------------
// Workspace layout (bytes), total ~10.2 MB:
//   0       header (64 ints): [0]=rec_count, [8..15]=f_acc, [16..23]=p_acc
//   256     cnt      (T*B*C floats = 196608 B)
//   196864  sel_e    (256 ints)
//   197888  sel_g    (256 floats)
//   198912  gsum     (128 floats)
//   199424  K        (N*C floats = 196608 B)
//   396032  A        (E*HF floats)
//   445184  Bc       (E*HF floats)
//   494336  const2   (E*C floats)
//   506624  inv2v    (E*C floats)
//   518912  rec      (REC_CAP*3 ints = 196608 B)
//   715520  w1t      (E*C*HF bf16 = 9437184 B)
// ---------------------------------------------------------------------------
extern "C" void kernel_launch(void* const* d_in, const int* in_sizes, int n_in,
                              void* d_out, int out_size, void* d_ws, size_t ws_size,
                              hipStream_t stream) {
  const float* x       = (const float*)d_in[0];
  const float* rw      = (const float*)d_in[1];
  const float* rb      = (const float*)d_in[2];
  const float* r_gamma = (const float*)d_in[3];
  const float* r_beta  = (const float*)d_in[4];
  const float* r_mean  = (const float*)d_in[5];
  const float* r_var   = (const float*)d_in[6];
  const float* w1      = (const float*)d_in[7];
  const float* b1      = (const float*)d_in[8];
  const float* g1      = (const float*)d_in[9];
  const float* be1     = (const float*)d_in[10];
  const float* m1      = (const float*)d_in[11];
  const float* v1      = (const float*)d_in[12];
  const float* w2      = (const float*)d_in[13];
  const float* b2      = (const float*)d_in[14];
  const float* g2      = (const float*)d_in[15];
  const float* be2     = (const float*)d_in[16];
  const float* m2      = (const float*)d_in[17];
  const float* v2      = (const float*)d_in[18];
  const float* taus    = (const float*)d_in[19];
  float* out = (float*)d_out;

  char* ws = (char*)d_ws;
  int*   header = (int*)ws;
  float* f_acc  = (float*)ws + 8;
  float* p_acc  = (float*)ws + 16;
  float* cnt    = (float*)(ws + 256);
  int*   sel_e  = (int*)(ws + 196864);
  float* sel_g  = (float*)(ws + 197888);
  float* gsum   = (float*)(ws + 198912);
  float* K      = (float*)(ws + 199424);
  float* A      = (float*)(ws + 396032);
  float* Bc     = (float*)(ws + 445184);
  float* const2 = (float*)(ws + 494336);
  float* inv2v  = (float*)(ws + 506624);
  int*   rec    = (int*)(ws + 518912);
  __hip_bfloat16* w1t = (__hip_bfloat16*)(ws + 715520);

  k_prep<<<48, 256, 0, stream>>>(b1, g1, be1, m1, v1, b2, g2, be2, m2, v2, taus,
                                 A, Bc, const2, inv2v, header);
  k_transpose<<<dim3(E_, C_ / 32, HF_ / 64), 256, 0, stream>>>(w1, w1t);
  k_lif<<<B_ * C_, 256, 0, stream>>>(x, cnt);
  k_router<<<N_, 64, 0, stream>>>(cnt, rw, rb, r_gamma, r_beta, r_mean, r_var,
                                  const2, sel_e, sel_g, gsum, K, f_acc, p_acc);
  k_expert1<<<dim3(2 * N_, 14), 256, 0, stream>>>(x, w1t, A, Bc, sel_e, taus,
                                                  rec, header);
  k_combine<<<(T_ * B_ * C_ * HW_ / 4 + 255) / 256, 256, 0, stream>>>(
      x, gsum, K, f_acc, p_acc, out, out + (out_size - 1));
  k_apply<<<64, 128, 0, stream>>>(rec, header, sel_e, sel_g, inv2v, w2, out);
}

// Round 2
// 258.049 us; speedup vs baseline: 1.0365x; 1.0365x over previous
//
#include <hip/hip_runtime.h>
#include <hip/hip_bf16.h>
#include <cstdint>

// Problem constants (from reference)
#define T_  4
#define B_  32
#define C_  384
#define HF_ 1536
#define HW_ 196
#define E_  8
#define N_  128           // T*B
#define REC_CAP 16384

#define LIFB (B_ * C_)        // 12288 lif blocks
#define TRB  (E_ * 12 * 24)   // 2304 transpose blocks
#define PRB  48               // prep blocks

// ---------------------------------------------------------------------------
// K1 (fused): LIF spike counts + BN-const folding + w1 transpose->bf16
//   blk <  LIFB          : LIF over T for one (b,c), ballot/popcount counting
//   blk <  LIFB+TRB      : LDS-tiled transpose w1 (E,HF,C) -> w1t (E,C,HF) bf16
//   else (PRB blocks)    : fold BN constants, zero header
// ---------------------------------------------------------------------------
__global__ __launch_bounds__(256) void k_lifprep(
    const float* __restrict__ x, float* __restrict__ cnt,
    const float* __restrict__ w1, __hip_bfloat16* __restrict__ w1t,
    const float* b1, const float* g1, const float* be1,
    const float* m1, const float* v1,
    const float* b2, const float* g2, const float* be2,
    const float* m2, const float* v2,
    const float* taus,
    float* A, float* Bc, float* const2, float* inv2v,
    int* header) {
  __shared__ float tile[64][33];
  __shared__ int c4[T_];
  int blk = blockIdx.x;
  int tid = threadIdx.x;

  if (blk < LIFB) {
    // ---- LIF ----
    if (tid < T_) c4[tid] = 0;
    __syncthreads();
    int bc = blk;
    bool act = tid < HW_;
    float v = 0.f;
    size_t base = (size_t)bc * HW_ + (act ? tid : 0);
    #pragma unroll
    for (int t = 0; t < T_; ++t) {
      float xv = act ? x[base + (size_t)t * B_ * C_ * HW_] : -1e30f;
      v = v + (xv - v) * 0.5f;                 // tau=2.0 exactly
      bool sp = (v - 1.0f >= 0.0f);
      if (sp) v = 0.f;
      unsigned long long m = __ballot(act && sp);
      if ((tid & 63) == 0) atomicAdd(&c4[t], __popcll(m));
    }
    __syncthreads();
    if (tid < T_) cnt[(size_t)tid * B_ * C_ + bc] = (float)c4[tid];
  } else if (blk < LIFB + TRB) {
    // ---- transpose w1 -> bf16 w1t ----
    int rem = blk - LIFB;
    int e = rem / 288, r2 = rem % 288;
    int ct = r2 / 24, ot = r2 % 24;
    int c0 = ct * 32, o0 = ot * 64;
    int cl = tid & 31, olb = tid >> 5;
    #pragma unroll
    for (int it = 0; it < 8; ++it) {
      int ol = olb + it * 8;
      tile[ol][cl] = w1[(size_t)(e * HF_ + o0 + ol) * C_ + c0 + cl];
    }
    __syncthreads();
    int ol2 = tid & 63, clb = tid >> 6;
    #pragma unroll
    for (int it = 0; it < 8; ++it) {
      int cl2 = clb + it * 4;
      w1t[(size_t)(e * C_ + c0 + cl2) * HF_ + o0 + ol2] =
          __float2bfloat16(tile[ol2][cl2]);
    }
  } else {
    // ---- prep ----
    int idx = (blk - LIFB - TRB) * 256 + tid;
    if (idx < 64) header[idx] = 0;
    if (idx < E_ * HF_) {
      int e = idx / HF_;
      float inv = g1[idx] / sqrtf(v1[idx] + 1e-5f);
      float sh  = be1[idx] - m1[idx] * inv;
      A[idx]  = inv;
      Bc[idx] = inv * b1[idx] + sh - taus[e];
    }
    if (idx < E_ * C_) {
      float inv = g2[idx] / sqrtf(v2[idx] + 1e-5f);
      const2[idx] = b2[idx] * inv + (be2[idx] - m2[idx] * inv);
      inv2v[idx]  = inv;
    }
  }
}

// ---------------------------------------------------------------------------
// K2: router logits -> softmax -> top-2 -> gate; aux accumulators; K[n,c]
// ---------------------------------------------------------------------------
__global__ void k_router(const float* __restrict__ cnt, const float* __restrict__ rw,
                         const float* rb, const float* rg, const float* rbeta,
                         const float* rmean, const float* rvar,
                         const float* __restrict__ const2,
                         int* sel_e, float* sel_g, float* gsum, float* K,
                         float* f_acc, float* p_acc) {
  __shared__ float sc[C_];
  __shared__ float part[64];
  __shared__ float lg[E_];
  __shared__ int s_i1, s_i2;
  __shared__ float s_g1, s_g2;
  int n = blockIdx.x, tid = threadIdx.x;  // 64 threads
  for (int c = tid; c < C_; c += 64) sc[c] = cnt[(size_t)n * C_ + c];
  __syncthreads();
  // 8 experts x 8 partial sums of 48 channels
  {
    int e = tid & 7, pp = tid >> 3;
    float d = 0.f;
    for (int c = pp * 48; c < pp * 48 + 48; ++c) d += rw[e * C_ + c] * sc[c];
    part[pp * 8 + e] = d;
  }
  __syncthreads();
  if (tid < E_) {
    float dot = 0.f;
    for (int p = 0; p < 8; ++p) dot += part[p * 8 + tid];
    float inv = rg[tid] / sqrtf(rvar[tid] + 1e-5f);
    lg[tid] = (dot * (1.0f / HW_) + rb[tid]) * inv + (rbeta[tid] - rmean[tid] * inv);
  }
  __syncthreads();
  if (tid == 0) {
    float m = lg[0];
    for (int e = 1; e < E_; ++e) m = fmaxf(m, lg[e]);
    float p[E_]; float s = 0.f;
    for (int e = 0; e < E_; ++e) { p[e] = expf(lg[e] - m); s += p[e]; }
    float invs = 1.0f / s;
    for (int e = 0; e < E_; ++e) p[e] *= invs;
    int i1 = 0;
    for (int e = 1; e < E_; ++e) if (p[e] > p[i1]) i1 = e;   // first-occurrence max
    int i2 = (i1 == 0) ? 1 : 0;
    for (int e = 0; e < E_; ++e) if (e != i1 && p[e] > p[i2]) i2 = e;
    float w = p[i1] + p[i2];
    float ga = p[i1] / w, gb = p[i2] / w;
    sel_e[2 * n] = i1; sel_e[2 * n + 1] = i2;
    sel_g[2 * n] = ga; sel_g[2 * n + 1] = gb;
    gsum[n] = ga + gb;
    s_i1 = i1; s_i2 = i2; s_g1 = ga; s_g2 = gb;
    atomicAdd(&f_acc[i1], 1.0f);
    atomicAdd(&f_acc[i2], 1.0f);
    for (int e = 0; e < E_; ++e) atomicAdd(&p_acc[e], p[e]);
  }
  __syncthreads();
  int i1 = s_i1, i2 = s_i2; float ga = s_g1, gb = s_g2;
  for (int c = tid; c < C_; c += 64)
    K[(size_t)n * C_ + c] = ga * const2[i1 * C_ + c] + gb * const2[i2 * C_ + c];
}

// ---------------------------------------------------------------------------
// K3 (hot): one block per (n, h). Stage x row once, process BOTH selected
// experts (spike list via ballot-compaction, gather w1t rows unrolled x4,
// threshold -> rare records), then write fused combine out = gsum*x + K.
// ---------------------------------------------------------------------------
__global__ __launch_bounds__(256) void k_main(
    const float* __restrict__ x, const __hip_bfloat16* __restrict__ w1t,
    const float* __restrict__ A, const float* __restrict__ Bc,
    const int* __restrict__ sel_e, const float* __restrict__ taus,
    const float* __restrict__ gsum, const float* __restrict__ K,
    float* __restrict__ out,
    int* __restrict__ rec, int* __restrict__ rec_count) {
  __shared__ float xs[14 * 385];   // xs[w*385 + c], +1 pad -> conflict-free
  __shared__ int slist[C_];
  __shared__ int snnz;
  int n = blockIdx.x, h = blockIdx.y;
  int tid = threadIdx.x;
  int lane = tid & 63, wave = tid >> 6;
  int tid3 = tid * 3;

  // stage x row h: xs[w*385 + c] = x[n, c, h, w]
  for (int idx = tid; idx < C_ * 14; idx += 256) {
    int c = idx / 14, w = idx - c * 14;
    xs[w * 385 + c] = x[((size_t)(n * C_ + c) * 14 + h) * 14 + w];
  }
  __syncthreads();

  for (int k = 0; k < 2; ++k) {
    int pair = 2 * n + k;
    int e = sel_e[pair];
    float tau = taus[e];
    float rA[6], rB[6];
    #pragma unroll
    for (int q = 0; q < 6; ++q) {
      int o = tid * 6 + q;
      rA[q] = A[e * HF_ + o];
      rB[q] = Bc[e * HF_ + o];
    }
    const uint32_t* wbase = (const uint32_t*)(w1t + (size_t)e * C_ * HF_);

    for (int w = 0; w < 14; ++w) {
      if (tid == 0) snnz = 0;
      __syncthreads();
      // build spike list: ballot-compaction, 1 atomic per wave-chunk
      for (int cb = wave * 64; cb < C_; cb += 256) {
        int c = cb + lane;
        bool sp = (xs[w * 385 + c] / tau - 1.0f >= 0.0f);  // s1 = spike(x/tau-1)
        unsigned long long m = __ballot(sp);
        int cntw = __popcll(m);
        int basep = 0;
        if (lane == 0 && cntw) basep = atomicAdd(&snnz, cntw);
        basep = __shfl(basep, 0);
        if (sp) {
          int pfx = __popcll(m & ((1ull << lane) - 1ull));
          slist[basep + pfx] = c;
        }
      }
      __syncthreads();
      int nnz = snnz;
      float S0 = 0, S1 = 0, S2 = 0, S3 = 0, S4 = 0, S5 = 0;
      int j = 0;
      for (; j + 4 <= nnz; j += 4) {             // 12 loads in flight
        const uint32_t* r0 = wbase + slist[j + 0] * (HF_ / 2) + tid3;
        const uint32_t* r1 = wbase + slist[j + 1] * (HF_ / 2) + tid3;
        const uint32_t* r2 = wbase + slist[j + 2] * (HF_ / 2) + tid3;
        const uint32_t* r3 = wbase + slist[j + 3] * (HF_ / 2) + tid3;
        uint32_t a0 = r0[0], a1 = r0[1], a2 = r0[2];
        uint32_t b0 = r1[0], b1 = r1[1], b2 = r1[2];
        uint32_t c0 = r2[0], c1 = r2[1], c2 = r2[2];
        uint32_t d0 = r3[0], d1 = r3[1], d2 = r3[2];
        S0 += __uint_as_float(a0 << 16) + __uint_as_float(b0 << 16) +
              __uint_as_float(c0 << 16) + __uint_as_float(d0 << 16);
        S1 += __uint_as_float(a0 & 0xffff0000u) + __uint_as_float(b0 & 0xffff0000u) +
              __uint_as_float(c0 & 0xffff0000u) + __uint_as_float(d0 & 0xffff0000u);
        S2 += __uint_as_float(a1 << 16) + __uint_as_float(b1 << 16) +
              __uint_as_float(c1 << 16) + __uint_as_float(d1 << 16);
        S3 += __uint_as_float(a1 & 0xffff0000u) + __uint_as_float(b1 & 0xffff0000u) +
              __uint_as_float(c1 & 0xffff0000u) + __uint_as_float(d1 & 0xffff0000u);
        S4 += __uint_as_float(a2 << 16) + __uint_as_float(b2 << 16) +
              __uint_as_float(c2 << 16) + __uint_as_float(d2 << 16);
        S5 += __uint_as_float(a2 & 0xffff0000u) + __uint_as_float(b2 & 0xffff0000u) +
              __uint_as_float(c2 & 0xffff0000u) + __uint_as_float(d2 & 0xffff0000u);
      }
      for (; j < nnz; ++j) {
        const uint32_t* row = wbase + slist[j] * (HF_ / 2) + tid3;
        uint32_t u0 = row[0], u1 = row[1], u2 = row[2];
        S0 += __uint_as_float(u0 << 16);
        S1 += __uint_as_float(u0 & 0xffff0000u);
        S2 += __uint_as_float(u1 << 16);
        S3 += __uint_as_float(u1 & 0xffff0000u);
        S4 += __uint_as_float(u2 << 16);
        S5 += __uint_as_float(u2 & 0xffff0000u);
      }
      float Sv[6] = {S0, S1, S2, S3, S4, S5};
      #pragma unroll
      for (int q = 0; q < 6; ++q) {
        float a = rA[q] * Sv[q] + rB[q];
        if (a >= 0.0f) {                         // layer-2 spike (rare)
          int ridx = atomicAdd(rec_count, 1);
          if (ridx < REC_CAP) {
            rec[ridx * 3 + 0] = pair;
            rec[ridx * 3 + 1] = h * 14 + w;
            rec[ridx * 3 + 2] = tid * 6 + q;
          }
        }
      }
      __syncthreads();
    }
  }

  // fused combine: out[n,c,h,w] = gsum[n]*x + K[n,c]
  float g = gsum[n];
  for (int idx = tid; idx < C_ * 14; idx += 256) {
    int c = idx / 14, w = idx - c * 14;
    out[((size_t)(n * C_ + c) * 14 + h) * 14 + w] =
        g * xs[w * 385 + c] + K[(size_t)n * C_ + c];
  }
}

// ---------------------------------------------------------------------------
// K4: apply the rare layer-2 spike records; write aux
// ---------------------------------------------------------------------------
__global__ void k_apply(const int* __restrict__ rec, const int* __restrict__ rec_count,
                        const int* __restrict__ sel_e, const float* __restrict__ sel_g,
                        const float* __restrict__ inv2v, const float* __restrict__ w2,
                        const float* f_acc, const float* p_acc,
                        float* __restrict__ out, float* aux_out) {
  int nrec = *rec_count;
  if (nrec > REC_CAP) nrec = REC_CAP;
  for (int r = blockIdx.x; r < nrec; r += gridDim.x) {
    int pair = rec[r * 3], p = rec[r * 3 + 1], o = rec[r * 3 + 2];
    int n = pair >> 1;
    int e = sel_e[pair];
    float g = sel_g[pair];
    for (int c = threadIdx.x; c < C_; c += blockDim.x) {
      float wv = w2[(size_t)(e * C_ + c) * HF_ + o];
      atomicAdd(&out[(size_t)(n * C_ + c) * HW_ + p], g * inv2v[e * C_ + c] * wv);
    }
  }
  if (blockIdx.x == 0 && threadIdx.x == 0) {
    float s = 0.f;
    for (int e = 0; e < E_; ++e)
      s += (f_acc[e] * (1.0f / N_)) * (p_acc[e] * (1.0f / N_));
    *aux_out = 0.01f * E_ * s;
  }
}

// ---------------------------------------------------------------------------
// Workspace layout (bytes), total ~10.2 MB
// ---------------------------------------------------------------------------
extern "C" void kernel_launch(void* const* d_in, const int* in_sizes, int n_in,
                              void* d_out, int out_size, void* d_ws, size_t ws_size,
                              hipStream_t stream) {
  const float* x       = (const float*)d_in[0];
  const float* rw      = (const float*)d_in[1];
  const float* rb      = (const float*)d_in[2];
  const float* r_gamma = (const float*)d_in[3];
  const float* r_beta  = (const float*)d_in[4];
  const float* r_mean  = (const float*)d_in[5];
  const float* r_var   = (const float*)d_in[6];
  const float* w1      = (const float*)d_in[7];
  const float* b1      = (const float*)d_in[8];
  const float* g1      = (const float*)d_in[9];
  const float* be1     = (const float*)d_in[10];
  const float* m1      = (const float*)d_in[11];
  const float* v1      = (const float*)d_in[12];
  const float* w2      = (const float*)d_in[13];
  const float* b2      = (const float*)d_in[14];
  const float* g2      = (const float*)d_in[15];
  const float* be2     = (const float*)d_in[16];
  const float* m2      = (const float*)d_in[17];
  const float* v2      = (const float*)d_in[18];
  const float* taus    = (const float*)d_in[19];
  float* out = (float*)d_out;

  char* ws = (char*)d_ws;
  int*   header = (int*)ws;
  float* f_acc  = (float*)ws + 8;
  float* p_acc  = (float*)ws + 16;
  float* cnt    = (float*)(ws + 256);
  int*   sel_e  = (int*)(ws + 196864);
  float* sel_g  = (float*)(ws + 197888);
  float* gsum   = (float*)(ws + 198912);
  float* K      = (float*)(ws + 199424);
  float* A      = (float*)(ws + 396032);
  float* Bc     = (float*)(ws + 445184);
  float* const2 = (float*)(ws + 494336);
  float* inv2v  = (float*)(ws + 506624);
  int*   rec    = (int*)(ws + 518912);
  __hip_bfloat16* w1t = (__hip_bfloat16*)(ws + 715520);

  k_lifprep<<<LIFB + TRB + PRB, 256, 0, stream>>>(
      x, cnt, w1, w1t, b1, g1, be1, m1, v1, b2, g2, be2, m2, v2, taus,
      A, Bc, const2, inv2v, header);
  k_router<<<N_, 64, 0, stream>>>(cnt, rw, rb, r_gamma, r_beta, r_mean, r_var,
                                  const2, sel_e, sel_g, gsum, K, f_acc, p_acc);
  k_main<<<dim3(N_, 14), 256, 0, stream>>>(x, w1t, A, Bc, sel_e, taus,
                                           gsum, K, out, rec, header);
  k_apply<<<64, 128, 0, stream>>>(rec, header, sel_e, sel_g, inv2v, w2,
                                  f_acc, p_acc, out, out + (out_size - 1));
}